// Round 13
// baseline (124.958 us; speedup 1.0000x reference)
//
#include <hip/hip_runtime.h>
#include <hip/hip_bf16.h>

typedef unsigned int u32;
typedef unsigned short u16;
typedef __bf16 bf16x8 __attribute__((ext_vector_type(8)));
typedef float f32x4 __attribute__((ext_vector_type(4)));

#define N_SPATIAL 4096
#define K_SEL 409
#define NBATCH 32
#define NCHAN 256
#define NTILE2 3    // 128x128 upper-tri tiles: (0,0),(0,1),(1,1)
#define NKSP 8      // K-split (K=512 per block) -> 768 blocks = 3/CU exactly

__constant__ int c2_TI[NTILE2] = {0,0,1};
__constant__ int c2_TJ[NTILE2] = {0,1,1};

__device__ __forceinline__ u16 f2bf(float f) {
    __hip_bfloat16 h = __float2bfloat16(f);
    return *reinterpret_cast<u16*>(&h);
}

__device__ __forceinline__ void gload_lds16(const void* g, void* l) {
    __builtin_amdgcn_global_load_lds((const __attribute__((address_space(1))) void*)g,
                                     (__attribute__((address_space(3))) void*)l, 16, 0, 0);
}

// ---------------- Kernel A: wave ballot-bisection top-k threshold + sparsify ----------------
// 4 independent waves per 256-thread block, one ROW per wave, 64 fp32/lane in registers.
// Values pinned via asm so the compiler CANNOT sink/rematerialize the loads into the
// 31-round bisection loop (r10/r11 failure: VGPR=40/16 proved re-loading per round).
// Zero LDS, zero barriers, zero atomics: count(|x|>=T) = popcount(ballot) per wave.
__global__ __launch_bounds__(256, 4) void topk_sparsify(const float* __restrict__ x,
                                                        u16* __restrict__ Fout) {
    const int t = threadIdx.x;
    const int lane = t & 63;
    const int wid = t >> 6;
    const int row = blockIdx.x * 4 + wid;          // one row per wave
    const float* xr = x + (size_t)row * N_SPATIAL;

    // 64 floats/lane, coalesced float4: slot (j,e) = x[(lane + 64*j)*4 + e]
    float4 v[16];
#pragma unroll
    for (int j = 0; j < 16; ++j)
        v[j] = reinterpret_cast<const float4*>(xr)[lane + 64 * j];
    // pin all 64 values into VGPRs — sever the load-derivation so no re-load is possible
#pragma unroll
    for (int j = 0; j < 16; ++j)
        asm volatile("" : "+v"(v[j].x), "+v"(v[j].y), "+v"(v[j].z), "+v"(v[j].w));

    // bisection on the abs bit pattern: largest T with count(|x| >= T) >= K_SEL
    u32 pref = 0;
    for (int p = 30; p >= 0; --p) {
        const float T = __uint_as_float(pref | (1u << p));
        int c = 0;
#pragma unroll
        for (int j = 0; j < 16; ++j) {
            c += __popcll(__ballot(fabsf(v[j].x) >= T));
            c += __popcll(__ballot(fabsf(v[j].y) >= T));
            c += __popcll(__ballot(fabsf(v[j].z) >= T));
            c += __popcll(__ballot(fabsf(v[j].w) >= T));
        }
        if (c >= K_SEL) pref |= (1u << p);         // wave-uniform
    }
    const float thr = __uint_as_float(pref);       // K-th largest |x|

    const size_t obase = (size_t)row * N_SPATIAL;
#pragma unroll
    for (int j = 0; j < 16; ++j) {
        ushort4 o;
        o.x = f2bf(fabsf(v[j].x) >= thr ? v[j].x : 0.0f);
        o.y = f2bf(fabsf(v[j].y) >= thr ? v[j].y : 0.0f);
        o.z = f2bf(fabsf(v[j].z) >= thr ? v[j].z : 0.0f);
        o.w = f2bf(fabsf(v[j].w) >= thr ? v[j].w : 0.0f);
        *reinterpret_cast<ushort4*>(Fout + obase + 4 * (lane + 64 * j)) = o;
    }
}

// ---------------- Kernel B: m97-structure gram partial (r4-proven), bf16 pg epilogue ----------------
// 128x128 tile, 4 waves x (4x4 frags), single-buffered 32 KiB LDS, 2 barriers/K-step.
// 768 blocks = 32 batches x 3 upper-tri tiles x 8 K-splits = exactly 3 blocks/CU.
__global__ __launch_bounds__(256) void gram_partial(const u16* __restrict__ F,
                                                    u16* __restrict__ pg) {
    __shared__ __align__(16) u16 As[128 * 64];
    __shared__ __align__(16) u16 Bs[128 * 64];

    const int t = threadIdx.x;
    const int lane = t & 63;
    const int wid = t >> 6;

    const int bid = blockIdx.x;
    const int xcd = bid & 7;
    const int idx = bid >> 3;           // 0..95
    const int b = (idx / 24) * 8 + xcd; // same-batch blocks share an XCD
    const int sub = idx % 24;
    const int tile = sub >> 3;          // 0..2
    const int ksp = sub & 7;            // 0..7
    const int ti = c2_TI[tile], tj = c2_TJ[tile];
    const bool diag = (ti == tj);
    const int kbase = ksp * 512;

    const u16* Fb = F + (size_t)b * NCHAN * N_SPATIAL;
    const int wr = wid >> 1, wc = wid & 1;   // wave's 64x64 quadrant

    // staging: chunk c=q*256+t; row=c>>3; LDS[row][s] holds global chunk s^(row&7)
    const u16* gA[4];
    const u16* gB[4];
#pragma unroll
    for (int q = 0; q < 4; ++q) {
        const int c = q * 256 + t;
        const int r = c >> 3;
        const int sc = ((c & 7) ^ (r & 7)) * 8;
        gA[q] = Fb + (size_t)(ti * 128 + r) * N_SPATIAL + kbase + sc;
        gB[q] = Fb + (size_t)(tj * 128 + r) * N_SPATIAL + kbase + sc;
    }

    f32x4 acc[4][4] = {};

    for (int kk = 0; kk < 8; ++kk) {        // K=512 per block, BK=64
        const int kb = kk * 64;
#pragma unroll
        for (int q = 0; q < 4; ++q) {
            gload_lds16(gA[q] + kb, As + (q * 256 + t) * 8);
            if (!diag) gload_lds16(gB[q] + kb, Bs + (q * 256 + t) * 8);
        }
        __syncthreads();                    // vmcnt(0) drain: staged data visible

        const u16* Bb = diag ? As : Bs;
#pragma unroll
        for (int ks = 0; ks < 2; ++ks) {
            const int kc0 = ks * 4 + (lane >> 4);
            bf16x8 a[4], bb[4];
#pragma unroll
            for (int m = 0; m < 4; ++m) {
                const int r = wr * 64 + m * 16 + (lane & 15);
                a[m] = *reinterpret_cast<const bf16x8*>(As + r * 64 + ((kc0 ^ (r & 7)) * 8));
            }
#pragma unroll
            for (int n = 0; n < 4; ++n) {
                const int r = wc * 64 + n * 16 + (lane & 15);
                bb[n] = *reinterpret_cast<const bf16x8*>(Bb + r * 64 + ((kc0 ^ (r & 7)) * 8));
            }
#pragma unroll
            for (int m = 0; m < 4; ++m)
#pragma unroll
                for (int n = 0; n < 4; ++n)
                    acc[m][n] = __builtin_amdgcn_mfma_f32_16x16x32_bf16(a[m], bb[n], acc[m][n], 0, 0, 0);
        }
        __syncthreads();                    // all waves done reading before next stage
    }

    // write 128x128 bf16 partial tile (partials ~O(10): bf16 err -> G err ~1e-9, negligible)
    u16* pt = pg + ((size_t)(b * NTILE2 + tile) * NKSP + ksp) * 16384;
#pragma unroll
    for (int m = 0; m < 4; ++m)
#pragma unroll
        for (int n = 0; n < 4; ++n) {
            const int col = wc * 64 + n * 16 + (lane & 15);
#pragma unroll
            for (int r = 0; r < 4; ++r) {
                const int rowi = wr * 64 + m * 16 + (lane >> 4) * 4 + r;
                pt[rowi * 128 + col] = f2bf(acc[m][n][r]);
            }
        }
}

// ---------------- Kernel C: combine 8 bf16 K-partials + fused loss with mirror ----------------
// 768 blocks = 32 batches x 3 tiles x 8 row-slices (16 rows each).
__global__ __launch_bounds__(256) void combine_loss(const u16* __restrict__ pg,
                                                    const float* __restrict__ T,
                                                    float* __restrict__ partials) {
    __shared__ float Gs[128][17];   // [col][row-within-slice], padded
    __shared__ float red[4];

    const int t = threadIdx.x;
    const int lane = t & 63;
    const int wid = t >> 6;
    const int bid = blockIdx.x;            // 0..767
    const int b = bid / (NTILE2 * 8);
    const int rest = bid % (NTILE2 * 8);
    const int tile = rest >> 3;
    const int q = rest & 7;                // 16-row slice
    const int ti = c2_TI[tile], tj = c2_TJ[tile];
    const bool diag = (ti == tj);
    const float invNorm = 1.0f / 33554432.0f;

    const u16* ptile = pg + (size_t)(b * NTILE2 + tile) * NKSP * 16384;
    const float* Tb = T + (size_t)b * (NCHAN * NCHAN);

    // thread tile: row r = t>>4 in [0,16), cols c0..c0+7 with c0 = (t&15)*8
    const int r = t >> 4;
    const int c0 = (t & 15) * 8;
    const int base = q * 2048 + r * 128 + c0;

    float G[8] = {};
#pragma unroll
    for (int sl = 0; sl < NKSP; ++sl) {
        bf16x8 pv = *reinterpret_cast<const bf16x8*>(ptile + sl * 16384 + base);
#pragma unroll
        for (int j = 0; j < 8; ++j) G[j] += (float)pv[j];
    }

    float s = 0.f;
    const int grow = ti * 128 + q * 16 + r;
#pragma unroll
    for (int j = 0; j < 8; ++j) {
        G[j] *= invNorm;
        const float d = Tb[grow * NCHAN + tj * 128 + c0 + j] - G[j];
        s += d * d;
        if (!diag) Gs[c0 + j][r] = G[j];
    }

    if (!diag) {
        __syncthreads();
        // mirror: element (row = tj*128+cc, col = ti*128+q*16+rr), G value = Gs[cc][rr]
        const int rr = t & 15;
        const int cc0 = t >> 4;
#pragma unroll
        for (int j = 0; j < 8; ++j) {
            const int cc = cc0 + 16 * j;
            const float d = Tb[(tj * 128 + cc) * NCHAN + ti * 128 + q * 16 + rr] - Gs[cc][rr];
            s += d * d;
        }
    }

#pragma unroll
    for (int dd = 32; dd >= 1; dd >>= 1) s += __shfl_down(s, dd);
    if (lane == 0) red[wid] = s;
    __syncthreads();
    if (t == 0) partials[bid] = red[0] + red[1] + red[2] + red[3];
}

// ---------------- Kernel D: deterministic final reduction over 768 partials ----------------
__global__ __launch_bounds__(256) void final_reduce(const float* __restrict__ partials,
                                                    float* __restrict__ out) {
    __shared__ float red[4];
    const int t = threadIdx.x;
    const int lane = t & 63;
    const int wid = t >> 6;
    float s = partials[t] + partials[t + 256] + partials[t + 512];
#pragma unroll
    for (int dd = 32; dd >= 1; dd >>= 1) s += __shfl_down(s, dd);
    if (lane == 0) red[wid] = s;
    __syncthreads();
    if (t == 0) out[0] = (red[0] + red[1] + red[2] + red[3]) * (1.0e9f / 2097152.0f);
}

extern "C" void kernel_launch(void* const* d_in, const int* in_sizes, int n_in,
                              void* d_out, int out_size, void* d_ws, size_t ws_size,
                              hipStream_t stream) {
    const float* x  = (const float*)d_in[0];           // (32,256,64,64) fp32
    const float* tg = (const float*)d_in[1];           // (32,256,256) fp32
    float* out = (float*)d_out;

    // ws layout: [0,4KiB) partials (768 f32... first 3KiB); [4KiB, +24MiB) bf16 pg; then F (64 MiB)
    float* partials = (float*)d_ws;
    u16* pg = (u16*)((char*)d_ws + 4096);
    u16* F = (u16*)((char*)d_ws + 4096 + (size_t)NBATCH * NTILE2 * NKSP * 16384 * 2);

    topk_sparsify<<<NBATCH * NCHAN / 4, 256, 0, stream>>>(x, F);
    gram_partial<<<NBATCH * NTILE2 * NKSP, 256, 0, stream>>>(F, pg);
    combine_loss<<<NBATCH * NTILE2 * 8, 256, 0, stream>>>(pg, tg, partials);
    final_reduce<<<1, 256, 0, stream>>>(partials, out);
}

// Round 14
// 102.858 us; speedup vs baseline: 1.2149x; 1.2149x over previous
//
#include <hip/hip_runtime.h>
#include <hip/hip_bf16.h>

typedef unsigned int u32;
typedef unsigned short u16;
typedef __bf16 bf16x8 __attribute__((ext_vector_type(8)));
typedef float f32x4 __attribute__((ext_vector_type(4)));

#define N_SPATIAL 4096
#define K_SEL 409
#define NBATCH 32
#define NCHAN 256
#define NTILE2 3    // 128x128 upper-tri tiles: (0,0),(0,1),(1,1)
#define NKSP 8      // K-split (K=512 per block) -> 768 blocks = 3/CU exactly

__constant__ int c2_TI[NTILE2] = {0,0,1};
__constant__ int c2_TJ[NTILE2] = {0,1,1};

__device__ __forceinline__ u16 f2bf(float f) {
    __hip_bfloat16 h = __float2bfloat16(f);
    return *reinterpret_cast<u16*>(&h);
}

__device__ __forceinline__ void gload_lds16(const void* g, void* l) {
    __builtin_amdgcn_global_load_lds((const __attribute__((address_space(1))) void*)g,
                                     (__attribute__((address_space(3))) void*)l, 16, 0, 0);
}

// ---------------- Kernel A: block ballot-bisection top-k, SMALL per-thread footprint ----------------
// One ROW per 256-thread block; 16 fp32/thread (16 data VGPRs) PINNED via asm so the
// compiler cannot re-load them inside the 31-round loop (r11: unpinned -> VGPR=16, reloads;
// r13: pin on 64-float/lane variant -> pressure blowout. This is the untested cell:
// small footprint + pin). Round loop kept rolled (#pragma unroll 1) to cap peak pressure.
__global__ __launch_bounds__(256) void topk_sparsify(const float* __restrict__ x,
                                                     u16* __restrict__ Fout) {
    __shared__ u32 wcnt[4];

    const int t = threadIdx.x;
    const int lane = t & 63;
    const int wid = t >> 6;
    const int row = blockIdx.x;
    const float* xr = x + (size_t)row * N_SPATIAL;

    float4 v[4];
#pragma unroll
    for (int j = 0; j < 4; ++j)
        v[j] = reinterpret_cast<const float4*>(xr)[t + 256 * j];
    // pin the 16 values into VGPRs: after this the compiler cannot derive them from loads
#pragma unroll
    for (int j = 0; j < 4; ++j)
        asm volatile("" : "+v"(v[j].x), "+v"(v[j].y), "+v"(v[j].z), "+v"(v[j].w));

    // bisection on the abs bit pattern: largest T with count(|x| >= T) >= K_SEL
    u32 pref = 0;
#pragma unroll 1
    for (int p = 30; p >= 0; --p) {
        const float T = __uint_as_float(pref | (1u << p));
        u32 c = 0;
#pragma unroll
        for (int j = 0; j < 4; ++j) {
            c += (u32)__popcll(__ballot(fabsf(v[j].x) >= T));
            c += (u32)__popcll(__ballot(fabsf(v[j].y) >= T));
            c += (u32)__popcll(__ballot(fabsf(v[j].z) >= T));
            c += (u32)__popcll(__ballot(fabsf(v[j].w) >= T));
        }
        if (lane == 0) wcnt[wid] = c;            // wave-uniform count
        __syncthreads();
        const u32 ctot = wcnt[0] + wcnt[1] + wcnt[2] + wcnt[3];
        if (ctot >= K_SEL) pref |= (1u << p);    // block-uniform decision
        __syncthreads();                         // wcnt reusable next round
    }
    const float thr = __uint_as_float(pref);     // K-th largest |x|

    const size_t obase = (size_t)row * N_SPATIAL;
#pragma unroll
    for (int j = 0; j < 4; ++j) {
        ushort4 o;
        o.x = f2bf(fabsf(v[j].x) >= thr ? v[j].x : 0.0f);
        o.y = f2bf(fabsf(v[j].y) >= thr ? v[j].y : 0.0f);
        o.z = f2bf(fabsf(v[j].z) >= thr ? v[j].z : 0.0f);
        o.w = f2bf(fabsf(v[j].w) >= thr ? v[j].w : 0.0f);
        *reinterpret_cast<ushort4*>(Fout + obase + 4 * t + 1024 * j) = o;
    }
}

// ---------------- Kernel B: m97-structure gram partial (r4-proven), bf16 pg epilogue ----------------
// 128x128 tile, 4 waves x (4x4 frags), single-buffered 32 KiB LDS, 2 barriers/K-step.
// 768 blocks = 32 batches x 3 upper-tri tiles x 8 K-splits = exactly 3 blocks/CU.
__global__ __launch_bounds__(256) void gram_partial(const u16* __restrict__ F,
                                                    u16* __restrict__ pg) {
    __shared__ __align__(16) u16 As[128 * 64];
    __shared__ __align__(16) u16 Bs[128 * 64];

    const int t = threadIdx.x;
    const int lane = t & 63;
    const int wid = t >> 6;

    const int bid = blockIdx.x;
    const int xcd = bid & 7;
    const int idx = bid >> 3;           // 0..95
    const int b = (idx / 24) * 8 + xcd; // same-batch blocks share an XCD
    const int sub = idx % 24;
    const int tile = sub >> 3;          // 0..2
    const int ksp = sub & 7;            // 0..7
    const int ti = c2_TI[tile], tj = c2_TJ[tile];
    const bool diag = (ti == tj);
    const int kbase = ksp * 512;

    const u16* Fb = F + (size_t)b * NCHAN * N_SPATIAL;
    const int wr = wid >> 1, wc = wid & 1;   // wave's 64x64 quadrant

    // staging: chunk c=q*256+t; row=c>>3; LDS[row][s] holds global chunk s^(row&7)
    const u16* gA[4];
    const u16* gB[4];
#pragma unroll
    for (int q = 0; q < 4; ++q) {
        const int c = q * 256 + t;
        const int r = c >> 3;
        const int sc = ((c & 7) ^ (r & 7)) * 8;
        gA[q] = Fb + (size_t)(ti * 128 + r) * N_SPATIAL + kbase + sc;
        gB[q] = Fb + (size_t)(tj * 128 + r) * N_SPATIAL + kbase + sc;
    }

    f32x4 acc[4][4] = {};

    for (int kk = 0; kk < 8; ++kk) {        // K=512 per block, BK=64
        const int kb = kk * 64;
#pragma unroll
        for (int q = 0; q < 4; ++q) {
            gload_lds16(gA[q] + kb, As + (q * 256 + t) * 8);
            if (!diag) gload_lds16(gB[q] + kb, Bs + (q * 256 + t) * 8);
        }
        __syncthreads();                    // vmcnt(0) drain: staged data visible

        const u16* Bb = diag ? As : Bs;
#pragma unroll
        for (int ks = 0; ks < 2; ++ks) {
            const int kc0 = ks * 4 + (lane >> 4);
            bf16x8 a[4], bb[4];
#pragma unroll
            for (int m = 0; m < 4; ++m) {
                const int r = wr * 64 + m * 16 + (lane & 15);
                a[m] = *reinterpret_cast<const bf16x8*>(As + r * 64 + ((kc0 ^ (r & 7)) * 8));
            }
#pragma unroll
            for (int n = 0; n < 4; ++n) {
                const int r = wc * 64 + n * 16 + (lane & 15);
                bb[n] = *reinterpret_cast<const bf16x8*>(Bb + r * 64 + ((kc0 ^ (r & 7)) * 8));
            }
#pragma unroll
            for (int m = 0; m < 4; ++m)
#pragma unroll
                for (int n = 0; n < 4; ++n)
                    acc[m][n] = __builtin_amdgcn_mfma_f32_16x16x32_bf16(a[m], bb[n], acc[m][n], 0, 0, 0);
        }
        __syncthreads();                    // all waves done reading before next stage
    }

    // write 128x128 bf16 partial tile (partials ~O(10): bf16 err -> G err ~1e-9, negligible)
    u16* pt = pg + ((size_t)(b * NTILE2 + tile) * NKSP + ksp) * 16384;
#pragma unroll
    for (int m = 0; m < 4; ++m)
#pragma unroll
        for (int n = 0; n < 4; ++n) {
            const int col = wc * 64 + n * 16 + (lane & 15);
#pragma unroll
            for (int r = 0; r < 4; ++r) {
                const int rowi = wr * 64 + m * 16 + (lane >> 4) * 4 + r;
                pt[rowi * 128 + col] = f2bf(acc[m][n][r]);
            }
        }
}

// ---------------- Kernel C: combine 8 bf16 K-partials + fused loss with mirror ----------------
// 768 blocks = 32 batches x 3 tiles x 8 row-slices (16 rows each).
__global__ __launch_bounds__(256) void combine_loss(const u16* __restrict__ pg,
                                                    const float* __restrict__ T,
                                                    float* __restrict__ partials) {
    __shared__ float Gs[128][17];   // [col][row-within-slice], padded
    __shared__ float red[4];

    const int t = threadIdx.x;
    const int lane = t & 63;
    const int wid = t >> 6;
    const int bid = blockIdx.x;            // 0..767
    const int b = bid / (NTILE2 * 8);
    const int rest = bid % (NTILE2 * 8);
    const int tile = rest >> 3;
    const int q = rest & 7;                // 16-row slice
    const int ti = c2_TI[tile], tj = c2_TJ[tile];
    const bool diag = (ti == tj);
    const float invNorm = 1.0f / 33554432.0f;

    const u16* ptile = pg + (size_t)(b * NTILE2 + tile) * NKSP * 16384;
    const float* Tb = T + (size_t)b * (NCHAN * NCHAN);

    // thread tile: row r = t>>4 in [0,16), cols c0..c0+7 with c0 = (t&15)*8
    const int r = t >> 4;
    const int c0 = (t & 15) * 8;
    const int base = q * 2048 + r * 128 + c0;

    float G[8] = {};
#pragma unroll
    for (int sl = 0; sl < NKSP; ++sl) {
        bf16x8 pv = *reinterpret_cast<const bf16x8*>(ptile + sl * 16384 + base);
#pragma unroll
        for (int j = 0; j < 8; ++j) G[j] += (float)pv[j];
    }

    float s = 0.f;
    const int grow = ti * 128 + q * 16 + r;
#pragma unroll
    for (int j = 0; j < 8; ++j) {
        G[j] *= invNorm;
        const float d = Tb[grow * NCHAN + tj * 128 + c0 + j] - G[j];
        s += d * d;
        if (!diag) Gs[c0 + j][r] = G[j];
    }

    if (!diag) {
        __syncthreads();
        // mirror: element (row = tj*128+cc, col = ti*128+q*16+rr), G value = Gs[cc][rr]
        const int rr = t & 15;
        const int cc0 = t >> 4;
#pragma unroll
        for (int j = 0; j < 8; ++j) {
            const int cc = cc0 + 16 * j;
            const float d = Tb[(tj * 128 + cc) * NCHAN + ti * 128 + q * 16 + rr] - Gs[cc][rr];
            s += d * d;
        }
    }

#pragma unroll
    for (int dd = 32; dd >= 1; dd >>= 1) s += __shfl_down(s, dd);
    if (lane == 0) red[wid] = s;
    __syncthreads();
    if (t == 0) partials[bid] = red[0] + red[1] + red[2] + red[3];
}

// ---------------- Kernel D: deterministic final reduction over 768 partials ----------------
__global__ __launch_bounds__(256) void final_reduce(const float* __restrict__ partials,
                                                    float* __restrict__ out) {
    __shared__ float red[4];
    const int t = threadIdx.x;
    const int lane = t & 63;
    const int wid = t >> 6;
    float s = partials[t] + partials[t + 256] + partials[t + 512];
#pragma unroll
    for (int dd = 32; dd >= 1; dd >>= 1) s += __shfl_down(s, dd);
    if (lane == 0) red[wid] = s;
    __syncthreads();
    if (t == 0) out[0] = (red[0] + red[1] + red[2] + red[3]) * (1.0e9f / 2097152.0f);
}

extern "C" void kernel_launch(void* const* d_in, const int* in_sizes, int n_in,
                              void* d_out, int out_size, void* d_ws, size_t ws_size,
                              hipStream_t stream) {
    const float* x  = (const float*)d_in[0];           // (32,256,64,64) fp32
    const float* tg = (const float*)d_in[1];           // (32,256,256) fp32
    float* out = (float*)d_out;

    // ws layout: [0,4KiB) partials (768 f32... first 3KiB); [4KiB, +24MiB) bf16 pg; then F (64 MiB)
    float* partials = (float*)d_ws;
    u16* pg = (u16*)((char*)d_ws + 4096);
    u16* F = (u16*)((char*)d_ws + 4096 + (size_t)NBATCH * NTILE2 * NKSP * 16384 * 2);

    topk_sparsify<<<NBATCH * NCHAN, 256, 0, stream>>>(x, F);
    gram_partial<<<NBATCH * NTILE2 * NKSP, 256, 0, stream>>>(F, pg);
    combine_loss<<<NBATCH * NTILE2 * 8, 256, 0, stream>>>(pg, tg, partials);
    final_reduce<<<1, 256, 0, stream>>>(partials, out);
}

// Round 15
// 61.784 us; speedup vs baseline: 2.0225x; 1.6648x over previous
//
#include <hip/hip_runtime.h>
#include <hip/hip_bf16.h>

typedef unsigned int u32;
typedef unsigned short u16;
typedef __bf16 bf16x8 __attribute__((ext_vector_type(8)));
typedef float f32x4 __attribute__((ext_vector_type(4)));

#define N_SPATIAL 4096
#define K_SEL 409
#define NBATCH 32
#define NCHAN 256
#define NTILE2 3    // 128x128 upper-tri tiles: (0,0),(0,1),(1,1)
#define NKSP 8      // K-split (K=512 per block) -> 768 blocks = 3/CU exactly

// value-domain histogram constants (all powers of two -> exact fp32 arithmetic)
#define LO_F 1.25f
#define S1_F 2048.0f                       // 2^11
#define W1_F 4.8828125e-4f                 // 2^-11
#define S2_F 8388608.0f                    // 2^23
#define W2_F 1.1920928955078125e-7f        // 2^-23
#define NB1 2048
#define NB2 4096

__constant__ int c2_TI[NTILE2] = {0,0,1};
__constant__ int c2_TJ[NTILE2] = {0,1,1};

__device__ __forceinline__ u16 f2bf(float f) {
    __hip_bfloat16 h = __float2bfloat16(f);
    return *reinterpret_cast<u16*>(&h);
}

__device__ __forceinline__ void gload_lds16(const void* g, void* l) {
    __builtin_amdgcn_global_load_lds((const __attribute__((address_space(1))) void*)g,
                                     (__attribute__((address_space(3))) void*)l, 16, 0, 0);
}

// ---------------- Kernel A: exact 2-level value-domain histogram top-k ----------------
// One ROW per 256-thread block, 16 fp32/thread. Pass 1: 2048 bins of width 2^-11 over
// [1.25, 2.25) — thresholds of N(0,1) rows land here w.p. ~1; ~0.4 values/bin => no atomic
// contention; below-range values SKIPPED (suffix scan needs only counts above). Pass 2:
// 4096 bins of width 2^-23 (1 ulp) inside the winning bin — Sterbenz-exact, so the k-th
// largest |x| is reconstructed exactly: thr = b1lo + j2*2^-23. Fallback: 31-round ballot
// bisection (block-uniform branch) if the threshold falls outside the range — never in
// practice, but correctness does not depend on the data distribution.
__global__ __launch_bounds__(256) void topk_sparsify(const float* __restrict__ x,
                                                     u16* __restrict__ Fout) {
    __shared__ u32 h1[NB1];
    __shared__ u32 h2[NB2];
    __shared__ u32 waveSum[4];
    __shared__ u32 wcnt[4];
    __shared__ u32 sh_j1, sh_krem, sh_found, sh_j2;

    const int t = threadIdx.x;
    const int lane = t & 63;
    const int wid = t >> 6;
    const int row = blockIdx.x;
    const float* xr = x + (size_t)row * N_SPATIAL;

    float4 v[4];
#pragma unroll
    for (int j = 0; j < 4; ++j)
        v[j] = reinterpret_cast<const float4*>(xr)[t + 256 * j];

    // zero both histograms (vectorized), init flags
#pragma unroll
    for (int j = 0; j < 2; ++j)
        *reinterpret_cast<uint4*>(&h1[(j * 256 + t) * 4]) = uint4{0, 0, 0, 0};
#pragma unroll
    for (int j = 0; j < 4; ++j)
        *reinterpret_cast<uint4*>(&h2[(j * 256 + t) * 4]) = uint4{0, 0, 0, 0};
    if (t == 0) { sh_found = 0; sh_j2 = 0; }
    __syncthreads();

    // ---- pass 1: coarse histogram ----
#pragma unroll
    for (int j = 0; j < 4; ++j) {
        const float* vf = reinterpret_cast<const float*>(&v[j]);
#pragma unroll
        for (int e = 0; e < 4; ++e) {
            const float a = fabsf(vf[e]);
            int b = (int)((a - LO_F) * S1_F);   // exact for a in [0.625, 2.5)
            b = min(b, NB1 - 1);
            if (b >= 0) atomicAdd(&h1[b], 1u);
        }
    }
    __syncthreads();

    // ---- scan 1 (suffix from top, r6-proven machinery), bpt = 8 ----
    {
        const int base = t * 8;
        u32 hloc[8];
        u32 csum = 0;
#pragma unroll
        for (int j = 0; j < 8; ++j) { hloc[j] = h1[base + j]; csum += hloc[j]; }
        u32 s = csum;
#pragma unroll
        for (int d = 1; d < 64; d <<= 1) {
            u32 o = __shfl_down(s, d);
            if (lane + d < 64) s += o;
        }
        if (lane == 0) waveSum[wid] = s;
        __syncthreads();
        u32 above = s - csum;
        for (int w2 = wid + 1; w2 < 4; ++w2) above += waveSum[w2];
        u32 cum = above;
#pragma unroll
        for (int j = 7; j >= 0; --j) {
            u32 c = hloc[j];
            if (cum < K_SEL && cum + c >= K_SEL) {
                sh_j1 = (u32)(base + j);
                sh_krem = K_SEL - cum;
                sh_found = 1;
            }
            cum += c;
        }
    }
    __syncthreads();

    float thr;
    if (sh_found && sh_j1 != NB1 - 1) {        // block-uniform fast path
        const float b1lo = LO_F + (float)sh_j1 * W1_F;   // exact dyadic
        const u32 krem1 = sh_krem;

        // ---- pass 2: 1-ulp histogram inside winning bin ----
#pragma unroll
        for (int j = 0; j < 4; ++j) {
            const float* vf = reinterpret_cast<const float*>(&v[j]);
#pragma unroll
            for (int e = 0; e < 4; ++e) {
                const float a = fabsf(vf[e]);
                const float o = (a - b1lo) * S2_F;       // exact (Sterbenz) when in-bin
                if (o >= 0.0f && o < (float)NB2) atomicAdd(&h2[(int)o], 1u);
            }
        }
        __syncthreads();

        // ---- scan 2, bpt = 16 ----
        {
            const int base = t * 16;
            u32 hloc[16];
            u32 csum = 0;
#pragma unroll
            for (int j = 0; j < 16; ++j) { hloc[j] = h2[base + j]; csum += hloc[j]; }
            u32 s = csum;
#pragma unroll
            for (int d = 1; d < 64; d <<= 1) {
                u32 o = __shfl_down(s, d);
                if (lane + d < 64) s += o;
            }
            if (lane == 0) waveSum[wid] = s;
            __syncthreads();
            u32 above = s - csum;
            for (int w2 = wid + 1; w2 < 4; ++w2) above += waveSum[w2];
            u32 cum = above;
#pragma unroll
            for (int j = 15; j >= 0; --j) {
                u32 c = hloc[j];
                if (cum < krem1 && cum + c >= krem1) sh_j2 = (u32)(base + j);
                cum += c;
            }
        }
        __syncthreads();
        thr = b1lo + (float)sh_j2 * W2_F;      // exact reconstruction of k-th |x|
    } else {
        // ---- fallback: 31-round ballot bisection (proven r11/r14 path) ----
        u32 pref = 0;
#pragma unroll 1
        for (int p = 30; p >= 0; --p) {
            const float T = __uint_as_float(pref | (1u << p));
            u32 c = 0;
#pragma unroll
            for (int j = 0; j < 4; ++j) {
                const float* vf = reinterpret_cast<const float*>(&v[j]);
                c += (u32)__popcll(__ballot(fabsf(vf[0]) >= T));
                c += (u32)__popcll(__ballot(fabsf(vf[1]) >= T));
                c += (u32)__popcll(__ballot(fabsf(vf[2]) >= T));
                c += (u32)__popcll(__ballot(fabsf(vf[3]) >= T));
            }
            if (lane == 0) wcnt[wid] = c;
            __syncthreads();
            const u32 ctot = wcnt[0] + wcnt[1] + wcnt[2] + wcnt[3];
            if (ctot >= K_SEL) pref |= (1u << p);
            __syncthreads();
        }
        thr = __uint_as_float(pref);
    }

    // ---- sparsify + bf16 write ----
    const size_t obase = (size_t)row * N_SPATIAL;
#pragma unroll
    for (int j = 0; j < 4; ++j) {
        const float* vf = reinterpret_cast<const float*>(&v[j]);
        ushort4 o;
        u16* op = reinterpret_cast<u16*>(&o);
#pragma unroll
        for (int e = 0; e < 4; ++e)
            op[e] = f2bf(fabsf(vf[e]) >= thr ? vf[e] : 0.0f);
        *reinterpret_cast<ushort4*>(Fout + obase + 4 * t + 1024 * j) = o;
    }
}

// ---------------- Kernel B: m97-structure gram partial (r4-proven), bf16 pg epilogue ----------------
// 128x128 tile, 4 waves x (4x4 frags), single-buffered 32 KiB LDS, 2 barriers/K-step.
// 768 blocks = 32 batches x 3 upper-tri tiles x 8 K-splits = exactly 3 blocks/CU.
__global__ __launch_bounds__(256) void gram_partial(const u16* __restrict__ F,
                                                    u16* __restrict__ pg) {
    __shared__ __align__(16) u16 As[128 * 64];
    __shared__ __align__(16) u16 Bs[128 * 64];

    const int t = threadIdx.x;
    const int lane = t & 63;
    const int wid = t >> 6;

    const int bid = blockIdx.x;
    const int xcd = bid & 7;
    const int idx = bid >> 3;           // 0..95
    const int b = (idx / 24) * 8 + xcd; // same-batch blocks share an XCD
    const int sub = idx % 24;
    const int tile = sub >> 3;          // 0..2
    const int ksp = sub & 7;            // 0..7
    const int ti = c2_TI[tile], tj = c2_TJ[tile];
    const bool diag = (ti == tj);
    const int kbase = ksp * 512;

    const u16* Fb = F + (size_t)b * NCHAN * N_SPATIAL;
    const int wr = wid >> 1, wc = wid & 1;   // wave's 64x64 quadrant

    // staging: chunk c=q*256+t; row=c>>3; LDS[row][s] holds global chunk s^(row&7)
    const u16* gA[4];
    const u16* gB[4];
#pragma unroll
    for (int q = 0; q < 4; ++q) {
        const int c = q * 256 + t;
        const int r = c >> 3;
        const int sc = ((c & 7) ^ (r & 7)) * 8;
        gA[q] = Fb + (size_t)(ti * 128 + r) * N_SPATIAL + kbase + sc;
        gB[q] = Fb + (size_t)(tj * 128 + r) * N_SPATIAL + kbase + sc;
    }

    f32x4 acc[4][4] = {};

    for (int kk = 0; kk < 8; ++kk) {        // K=512 per block, BK=64
        const int kb = kk * 64;
#pragma unroll
        for (int q = 0; q < 4; ++q) {
            gload_lds16(gA[q] + kb, As + (q * 256 + t) * 8);
            if (!diag) gload_lds16(gB[q] + kb, Bs + (q * 256 + t) * 8);
        }
        __syncthreads();                    // vmcnt(0) drain: staged data visible

        const u16* Bb = diag ? As : Bs;
#pragma unroll
        for (int ks = 0; ks < 2; ++ks) {
            const int kc0 = ks * 4 + (lane >> 4);
            bf16x8 a[4], bb[4];
#pragma unroll
            for (int m = 0; m < 4; ++m) {
                const int r = wr * 64 + m * 16 + (lane & 15);
                a[m] = *reinterpret_cast<const bf16x8*>(As + r * 64 + ((kc0 ^ (r & 7)) * 8));
            }
#pragma unroll
            for (int n = 0; n < 4; ++n) {
                const int r = wc * 64 + n * 16 + (lane & 15);
                bb[n] = *reinterpret_cast<const bf16x8*>(Bb + r * 64 + ((kc0 ^ (r & 7)) * 8));
            }
#pragma unroll
            for (int m = 0; m < 4; ++m)
#pragma unroll
                for (int n = 0; n < 4; ++n)
                    acc[m][n] = __builtin_amdgcn_mfma_f32_16x16x32_bf16(a[m], bb[n], acc[m][n], 0, 0, 0);
        }
        __syncthreads();                    // all waves done reading before next stage
    }

    // write 128x128 bf16 partial tile (partials ~O(10): bf16 err -> G err ~1e-9, negligible)
    u16* pt = pg + ((size_t)(b * NTILE2 + tile) * NKSP + ksp) * 16384;
#pragma unroll
    for (int m = 0; m < 4; ++m)
#pragma unroll
        for (int n = 0; n < 4; ++n) {
            const int col = wc * 64 + n * 16 + (lane & 15);
#pragma unroll
            for (int r = 0; r < 4; ++r) {
                const int rowi = wr * 64 + m * 16 + (lane >> 4) * 4 + r;
                pt[rowi * 128 + col] = f2bf(acc[m][n][r]);
            }
        }
}

// ---------------- Kernel C: combine 8 bf16 K-partials + fused loss with mirror ----------------
// 768 blocks = 32 batches x 3 tiles x 8 row-slices (16 rows each).
__global__ __launch_bounds__(256) void combine_loss(const u16* __restrict__ pg,
                                                    const float* __restrict__ T,
                                                    float* __restrict__ partials) {
    __shared__ float Gs[128][17];   // [col][row-within-slice], padded
    __shared__ float red[4];

    const int t = threadIdx.x;
    const int lane = t & 63;
    const int wid = t >> 6;
    const int bid = blockIdx.x;            // 0..767
    const int b = bid / (NTILE2 * 8);
    const int rest = bid % (NTILE2 * 8);
    const int tile = rest >> 3;
    const int q = rest & 7;                // 16-row slice
    const int ti = c2_TI[tile], tj = c2_TJ[tile];
    const bool diag = (ti == tj);
    const float invNorm = 1.0f / 33554432.0f;

    const u16* ptile = pg + (size_t)(b * NTILE2 + tile) * NKSP * 16384;
    const float* Tb = T + (size_t)b * (NCHAN * NCHAN);

    // thread tile: row r = t>>4 in [0,16), cols c0..c0+7 with c0 = (t&15)*8
    const int r = t >> 4;
    const int c0 = (t & 15) * 8;
    const int base = q * 2048 + r * 128 + c0;

    float G[8] = {};
#pragma unroll
    for (int sl = 0; sl < NKSP; ++sl) {
        bf16x8 pv = *reinterpret_cast<const bf16x8*>(ptile + sl * 16384 + base);
#pragma unroll
        for (int j = 0; j < 8; ++j) G[j] += (float)pv[j];
    }

    float s = 0.f;
    const int grow = ti * 128 + q * 16 + r;
#pragma unroll
    for (int j = 0; j < 8; ++j) {
        G[j] *= invNorm;
        const float d = Tb[grow * NCHAN + tj * 128 + c0 + j] - G[j];
        s += d * d;
        if (!diag) Gs[c0 + j][r] = G[j];
    }

    if (!diag) {
        __syncthreads();
        // mirror: element (row = tj*128+cc, col = ti*128+q*16+rr), G value = Gs[cc][rr]
        const int rr = t & 15;
        const int cc0 = t >> 4;
#pragma unroll
        for (int j = 0; j < 8; ++j) {
            const int cc = cc0 + 16 * j;
            const float d = Tb[(tj * 128 + cc) * NCHAN + ti * 128 + q * 16 + rr] - Gs[cc][rr];
            s += d * d;
        }
    }

#pragma unroll
    for (int dd = 32; dd >= 1; dd >>= 1) s += __shfl_down(s, dd);
    if (lane == 0) red[wid] = s;
    __syncthreads();
    if (t == 0) partials[bid] = red[0] + red[1] + red[2] + red[3];
}

// ---------------- Kernel D: deterministic final reduction over 768 partials ----------------
__global__ __launch_bounds__(256) void final_reduce(const float* __restrict__ partials,
                                                    float* __restrict__ out) {
    __shared__ float red[4];
    const int t = threadIdx.x;
    const int lane = t & 63;
    const int wid = t >> 6;
    float s = partials[t] + partials[t + 256] + partials[t + 512];
#pragma unroll
    for (int dd = 32; dd >= 1; dd >>= 1) s += __shfl_down(s, dd);
    if (lane == 0) red[wid] = s;
    __syncthreads();
    if (t == 0) out[0] = (red[0] + red[1] + red[2] + red[3]) * (1.0e9f / 2097152.0f);
}

extern "C" void kernel_launch(void* const* d_in, const int* in_sizes, int n_in,
                              void* d_out, int out_size, void* d_ws, size_t ws_size,
                              hipStream_t stream) {
    const float* x  = (const float*)d_in[0];           // (32,256,64,64) fp32
    const float* tg = (const float*)d_in[1];           // (32,256,256) fp32
    float* out = (float*)d_out;

    // ws layout: [0,4KiB) partials (768 f32... first 3KiB); [4KiB, +24MiB) bf16 pg; then F (64 MiB)
    float* partials = (float*)d_ws;
    u16* pg = (u16*)((char*)d_ws + 4096);
    u16* F = (u16*)((char*)d_ws + 4096 + (size_t)NBATCH * NTILE2 * NKSP * 16384 * 2);

    topk_sparsify<<<NBATCH * NCHAN, 256, 0, stream>>>(x, F);
    gram_partial<<<NBATCH * NTILE2 * NKSP, 256, 0, stream>>>(F, pg);
    combine_loss<<<NBATCH * NTILE2 * 8, 256, 0, stream>>>(pg, tg, partials);
    final_reduce<<<1, 256, 0, stream>>>(partials, out);
}

// Round 17
// 57.560 us; speedup vs baseline: 2.1709x; 1.0734x over previous
//
#include <hip/hip_runtime.h>
#include <hip/hip_bf16.h>

typedef unsigned int u32;
typedef unsigned short u16;
typedef unsigned char u8;
typedef long long i64;
typedef __bf16 bf16x8 __attribute__((ext_vector_type(8)));
typedef float f32x4 __attribute__((ext_vector_type(4)));

#define N_SPATIAL 4096
#define K_SEL 409
#define NBATCH 32
#define NCHAN 256
#define NTILE2 3    // 128x128 upper-tri tiles: (0,0),(0,1),(1,1)
#define NKSP 8      // K-split (K=512 per block) -> 768 blocks = 3/CU exactly

// value-domain histogram constants (all powers of two -> exact fp32 arithmetic)
#define LO_F 1.25f
#define S1_F 2048.0f                       // 2^11
#define W1_F 4.8828125e-4f                 // 2^-11
#define S2_F 8388608.0f                    // 2^23
#define W2_F 1.1920928955078125e-7f        // 2^-23
#define NB1 2048
#define NB2 4096

__constant__ int c2_TI[NTILE2] = {0,0,1};
__constant__ int c2_TJ[NTILE2] = {0,1,1};

__device__ __forceinline__ u16 f2bf(float f) {
    __hip_bfloat16 h = __float2bfloat16(f);
    return *reinterpret_cast<u16*>(&h);
}

__device__ __forceinline__ void gload_lds16(const void* g, void* l) {
    __builtin_amdgcn_global_load_lds((const __attribute__((address_space(1))) void*)g,
                                     (__attribute__((address_space(3))) void*)l, 16, 0, 0);
}

// ---------------- Kernel A: exact 2-level value-domain histogram top-k -> fp8 F ----------------
// r15-proven selection machinery; output F stored as OCP e4m3 via HW cvt (self-consistent
// with the fp8 MFMA decode — encoding details cancel). 4B/thread/iter coalesced u32 stores.
__global__ __launch_bounds__(256) void topk_sparsify(const float* __restrict__ x,
                                                     u8* __restrict__ Fout) {
    __shared__ u32 h1[NB1];
    __shared__ u32 h2[NB2];
    __shared__ u32 waveSum[4];
    __shared__ u32 wcnt[4];
    __shared__ u32 sh_j1, sh_krem, sh_found, sh_j2;

    const int t = threadIdx.x;
    const int lane = t & 63;
    const int wid = t >> 6;
    const int row = blockIdx.x;
    const float* xr = x + (size_t)row * N_SPATIAL;

    float4 v[4];
#pragma unroll
    for (int j = 0; j < 4; ++j)
        v[j] = reinterpret_cast<const float4*>(xr)[t + 256 * j];

#pragma unroll
    for (int j = 0; j < 2; ++j)
        *reinterpret_cast<uint4*>(&h1[(j * 256 + t) * 4]) = uint4{0, 0, 0, 0};
#pragma unroll
    for (int j = 0; j < 4; ++j)
        *reinterpret_cast<uint4*>(&h2[(j * 256 + t) * 4]) = uint4{0, 0, 0, 0};
    if (t == 0) { sh_found = 0; sh_j2 = 0; }
    __syncthreads();

    // ---- pass 1: coarse histogram over [1.25, 2.25) ----
#pragma unroll
    for (int j = 0; j < 4; ++j) {
        const float* vf = reinterpret_cast<const float*>(&v[j]);
#pragma unroll
        for (int e = 0; e < 4; ++e) {
            const float a = fabsf(vf[e]);
            int b = (int)((a - LO_F) * S1_F);
            b = min(b, NB1 - 1);
            if (b >= 0) atomicAdd(&h1[b], 1u);
        }
    }
    __syncthreads();

    // ---- scan 1 (suffix from top), bpt = 8 ----
    {
        const int base = t * 8;
        u32 hloc[8];
        u32 csum = 0;
#pragma unroll
        for (int j = 0; j < 8; ++j) { hloc[j] = h1[base + j]; csum += hloc[j]; }
        u32 s = csum;
#pragma unroll
        for (int d = 1; d < 64; d <<= 1) {
            u32 o = __shfl_down(s, d);
            if (lane + d < 64) s += o;
        }
        if (lane == 0) waveSum[wid] = s;
        __syncthreads();
        u32 above = s - csum;
        for (int w2 = wid + 1; w2 < 4; ++w2) above += waveSum[w2];
        u32 cum = above;
#pragma unroll
        for (int j = 7; j >= 0; --j) {
            u32 c = hloc[j];
            if (cum < K_SEL && cum + c >= K_SEL) {
                sh_j1 = (u32)(base + j);
                sh_krem = K_SEL - cum;
                sh_found = 1;
            }
            cum += c;
        }
    }
    __syncthreads();

    float thr;
    if (sh_found && sh_j1 != NB1 - 1) {
        const float b1lo = LO_F + (float)sh_j1 * W1_F;
        const u32 krem1 = sh_krem;

        // ---- pass 2: 1-ulp histogram inside winning bin ----
#pragma unroll
        for (int j = 0; j < 4; ++j) {
            const float* vf = reinterpret_cast<const float*>(&v[j]);
#pragma unroll
            for (int e = 0; e < 4; ++e) {
                const float a = fabsf(vf[e]);
                const float o = (a - b1lo) * S2_F;
                if (o >= 0.0f && o < (float)NB2) atomicAdd(&h2[(int)o], 1u);
            }
        }
        __syncthreads();

        // ---- scan 2, bpt = 16 ----
        {
            const int base = t * 16;
            u32 hloc[16];
            u32 csum = 0;
#pragma unroll
            for (int j = 0; j < 16; ++j) { hloc[j] = h2[base + j]; csum += hloc[j]; }
            u32 s = csum;
#pragma unroll
            for (int d = 1; d < 64; d <<= 1) {
                u32 o = __shfl_down(s, d);
                if (lane + d < 64) s += o;
            }
            if (lane == 0) waveSum[wid] = s;
            __syncthreads();
            u32 above = s - csum;
            for (int w2 = wid + 1; w2 < 4; ++w2) above += waveSum[w2];
            u32 cum = above;
#pragma unroll
            for (int j = 15; j >= 0; --j) {
                u32 c = hloc[j];
                if (cum < krem1 && cum + c >= krem1) sh_j2 = (u32)(base + j);
                cum += c;
            }
        }
        __syncthreads();
        thr = b1lo + (float)sh_j2 * W2_F;
    } else {
        // ---- fallback: 31-round ballot bisection ----
        u32 pref = 0;
#pragma unroll 1
        for (int p = 30; p >= 0; --p) {
            const float T = __uint_as_float(pref | (1u << p));
            u32 c = 0;
#pragma unroll
            for (int j = 0; j < 4; ++j) {
                const float* vf = reinterpret_cast<const float*>(&v[j]);
                c += (u32)__popcll(__ballot(fabsf(vf[0]) >= T));
                c += (u32)__popcll(__ballot(fabsf(vf[1]) >= T));
                c += (u32)__popcll(__ballot(fabsf(vf[2]) >= T));
                c += (u32)__popcll(__ballot(fabsf(vf[3]) >= T));
            }
            if (lane == 0) wcnt[wid] = c;
            __syncthreads();
            const u32 ctot = wcnt[0] + wcnt[1] + wcnt[2] + wcnt[3];
            if (ctot >= K_SEL) pref |= (1u << p);
            __syncthreads();
        }
        thr = __uint_as_float(pref);
    }

    // ---- sparsify + fp8 write (HW cvt_pk, 2 values/instr) ----
    u32* o32 = reinterpret_cast<u32*>(Fout + (size_t)row * N_SPATIAL);
#pragma unroll
    for (int j = 0; j < 4; ++j) {
        const float* vf = reinterpret_cast<const float*>(&v[j]);
        float f0 = fabsf(vf[0]) >= thr ? vf[0] : 0.0f;
        float f1 = fabsf(vf[1]) >= thr ? vf[1] : 0.0f;
        float f2 = fabsf(vf[2]) >= thr ? vf[2] : 0.0f;
        float f3 = fabsf(vf[3]) >= thr ? vf[3] : 0.0f;
        u32 lo = (u32)__builtin_amdgcn_cvt_pk_fp8_f32(f0, f1, 0, false);
        u32 hi = (u32)__builtin_amdgcn_cvt_pk_fp8_f32(f2, f3, 0, false);
        o32[t + 256 * j] = (lo & 0xffffu) | (hi << 16);
    }
}

// ---------------- Kernel B: fp8 gram partial (m97 structure), bf16 pg epilogue ----------------
// 128x128 tile, 4 waves x (4x4 frags), single-buffered 32 KiB LDS (2 x 16 KiB fp8 panels),
// BK=128, 2 barriers/K-step. 768 blocks = 32 x 3 x 8 K-splits. 16B-chunk XOR swizzle
// (both-sides); fragments via ds_read_b64 (8 fp8 = K-chunk of the 16x16x32 fp8 MFMA).
__global__ __launch_bounds__(256) void gram_partial(const u8* __restrict__ F,
                                                    u16* __restrict__ pg) {
    __shared__ __align__(16) u8 As[128 * 128];
    __shared__ __align__(16) u8 Bs[128 * 128];

    const int t = threadIdx.x;
    const int lane = t & 63;
    const int wid = t >> 6;

    const int bid = blockIdx.x;
    const int xcd = bid & 7;
    const int idx = bid >> 3;           // 0..95
    const int b = (idx / 24) * 8 + xcd;
    const int sub = idx % 24;
    const int tile = sub >> 3;          // 0..2
    const int ksp = sub & 7;            // 0..7
    const int ti = c2_TI[tile], tj = c2_TJ[tile];
    const bool diag = (ti == tj);
    const int kbase = ksp * 512;        // elements == bytes (fp8)

    const u8* Fb = F + (size_t)b * NCHAN * N_SPATIAL;
    const int wr = wid >> 1, wc = wid & 1;

    // staging: LDS chunk L = q*256+t (16B); row r = L>>3 (8 chunks/row of 128B);
    // LDS[r][cir] holds global chunk cir^(r&7)  (16B-granular XOR — gload-compatible)
    const u8* gA[4];
    const u8* gB[4];
#pragma unroll
    for (int q = 0; q < 4; ++q) {
        const int L = q * 256 + t;
        const int r = L >> 3;
        const int cir = ((L & 7) ^ (r & 7)) * 16;
        gA[q] = Fb + (size_t)(ti * 128 + r) * N_SPATIAL + kbase + cir;
        gB[q] = Fb + (size_t)(tj * 128 + r) * N_SPATIAL + kbase + cir;
    }

    f32x4 acc[4][4] = {};

    for (int kk = 0; kk < 4; ++kk) {        // K=512 per block, BK=128
        const int kb = kk * 128;
#pragma unroll
        for (int q = 0; q < 4; ++q) {
            gload_lds16(gA[q] + kb, As + (q * 256 + t) * 16);
            if (!diag) gload_lds16(gB[q] + kb, Bs + (q * 256 + t) * 16);
        }
        __syncthreads();                    // vmcnt(0) drain: staged data visible

        const u8* Bb = diag ? As : Bs;
        const int halfk = lane >> 4;        // 8B slot within each 32B K-group
#pragma unroll
        for (int ks = 0; ks < 4; ++ks) {    // 4 x K=32 MFMA per BK=128
            const int s = ks * 4 + halfk;   // 8B slot in 128B row
            const int ch = s >> 1, hf = (s & 1) * 8;
            i64 a[4], bb[4];
#pragma unroll
            for (int m = 0; m < 4; ++m) {
                const int r = wr * 64 + m * 16 + (lane & 15);
                a[m] = *reinterpret_cast<const i64*>(As + r * 128 + ((ch ^ (r & 7)) * 16) + hf);
            }
#pragma unroll
            for (int n = 0; n < 4; ++n) {
                const int r = wc * 64 + n * 16 + (lane & 15);
                bb[n] = *reinterpret_cast<const i64*>(Bb + r * 128 + ((ch ^ (r & 7)) * 16) + hf);
            }
#pragma unroll
            for (int m = 0; m < 4; ++m)
#pragma unroll
                for (int n = 0; n < 4; ++n)
                    acc[m][n] = __builtin_amdgcn_mfma_f32_16x16x32_fp8_fp8(a[m], bb[n], acc[m][n], 0, 0, 0);
        }
        __syncthreads();
    }

    // write 128x128 bf16 partial tile
    u16* pt = pg + ((size_t)(b * NTILE2 + tile) * NKSP + ksp) * 16384;
#pragma unroll
    for (int m = 0; m < 4; ++m)
#pragma unroll
        for (int n = 0; n < 4; ++n) {
            const int col = wc * 64 + n * 16 + (lane & 15);
#pragma unroll
            for (int r = 0; r < 4; ++r) {
                const int rowi = wr * 64 + m * 16 + (lane >> 4) * 4 + r;
                pt[rowi * 128 + col] = f2bf(acc[m][n][r]);
            }
        }
}

// ---------------- Kernel C: combine 8 bf16 K-partials + fused loss with mirror ----------------
__global__ __launch_bounds__(256) void combine_loss(const u16* __restrict__ pg,
                                                    const float* __restrict__ T,
                                                    float* __restrict__ partials) {
    __shared__ float Gs[128][17];
    __shared__ float red[4];

    const int t = threadIdx.x;
    const int lane = t & 63;
    const int wid = t >> 6;
    const int bid = blockIdx.x;            // 0..767
    const int b = bid / (NTILE2 * 8);
    const int rest = bid % (NTILE2 * 8);
    const int tile = rest >> 3;
    const int q = rest & 7;
    const int ti = c2_TI[tile], tj = c2_TJ[tile];
    const bool diag = (ti == tj);
    const float invNorm = 1.0f / 33554432.0f;

    const u16* ptile = pg + (size_t)(b * NTILE2 + tile) * NKSP * 16384;
    const float* Tb = T + (size_t)b * (NCHAN * NCHAN);

    const int r = t >> 4;
    const int c0 = (t & 15) * 8;
    const int base = q * 2048 + r * 128 + c0;

    float G[8] = {};
#pragma unroll
    for (int sl = 0; sl < NKSP; ++sl) {
        bf16x8 pv = *reinterpret_cast<const bf16x8*>(ptile + sl * 16384 + base);
#pragma unroll
        for (int j = 0; j < 8; ++j) G[j] += (float)pv[j];
    }

    float s = 0.f;
    const int grow = ti * 128 + q * 16 + r;
#pragma unroll
    for (int j = 0; j < 8; ++j) {
        G[j] *= invNorm;
        const float d = Tb[grow * NCHAN + tj * 128 + c0 + j] - G[j];
        s += d * d;
        if (!diag) Gs[c0 + j][r] = G[j];
    }

    if (!diag) {
        __syncthreads();
        const int rr = t & 15;
        const int cc0 = t >> 4;
#pragma unroll
        for (int j = 0; j < 8; ++j) {
            const int cc = cc0 + 16 * j;
            const float d = Tb[(tj * 128 + cc) * NCHAN + ti * 128 + q * 16 + rr] - Gs[cc][rr];
            s += d * d;
        }
    }

#pragma unroll
    for (int dd = 32; dd >= 1; dd >>= 1) s += __shfl_down(s, dd);
    if (lane == 0) red[wid] = s;
    __syncthreads();
    if (t == 0) partials[bid] = red[0] + red[1] + red[2] + red[3];
}

// ---------------- Kernel D: deterministic final reduction over 768 partials ----------------
__global__ __launch_bounds__(256) void final_reduce(const float* __restrict__ partials,
                                                    float* __restrict__ out) {
    __shared__ float red[4];
    const int t = threadIdx.x;
    const int lane = t & 63;
    const int wid = t >> 6;
    float s = partials[t] + partials[t + 256] + partials[t + 512];
#pragma unroll
    for (int dd = 32; dd >= 1; dd >>= 1) s += __shfl_down(s, dd);
    if (lane == 0) red[wid] = s;
    __syncthreads();
    if (t == 0) out[0] = (red[0] + red[1] + red[2] + red[3]) * (1.0e9f / 2097152.0f);
}

extern "C" void kernel_launch(void* const* d_in, const int* in_sizes, int n_in,
                              void* d_out, int out_size, void* d_ws, size_t ws_size,
                              hipStream_t stream) {
    const float* x  = (const float*)d_in[0];           // (32,256,64,64) fp32
    const float* tg = (const float*)d_in[1];           // (32,256,256) fp32
    float* out = (float*)d_out;

    // ws layout: [0,4KiB) partials; [4KiB, +24MiB) bf16 pg; then F as fp8 (32 MiB)
    float* partials = (float*)d_ws;
    u16* pg = (u16*)((char*)d_ws + 4096);
    u8* F = (u8*)((char*)d_ws + 4096 + (size_t)NBATCH * NTILE2 * NKSP * 16384 * 2);

    topk_sparsify<<<NBATCH * NCHAN, 256, 0, stream>>>(x, F);
    gram_partial<<<NBATCH * NTILE2 * NKSP, 256, 0, stream>>>(F, pg);
    combine_loss<<<NBATCH * NTILE2 * 8, 256, 0, stream>>>(pg, tg, partials);
    final_reduce<<<1, 256, 0, stream>>>(partials, out);
}